// Round 1
// baseline (364.481 us; speedup 1.0000x reference)
//
#include <hip/hip_runtime.h>
#include <hip/hip_bf16.h>
#include <math.h>

#define TOKENS 2048
#define HID 2048
#define FFN 1024
#define NEXP 16
#define NTOT 32
#define KSEL 4
#define RSCALE 2.5f

typedef __bf16 v8bf __attribute__((ext_vector_type(8)));
typedef float v4f __attribute__((ext_vector_type(4)));
typedef unsigned short u16x8v __attribute__((ext_vector_type(8)));

static __device__ __forceinline__ v8bf zero_v8bf() {
  u16x8v z = {0, 0, 0, 0, 0, 0, 0, 0};
  return __builtin_bit_cast(v8bf, z);
}

// ---------------------------------------------------------------------------
// Router: one block per token.
//  - exact fp32 logits (32 dots of length 2048)
//  - softmax + bias, top-4 (tie: lowest index, matches jax.lax.top_k)
//  - zero-experts (id>=16): weight accumulated into zero_total
//  - writes out[t,:] = zero_total * hidden[t,:]  (full overwrite of d_out)
//  - writes bf16 copy of hidden row
//  - appends (token, weight) to per-expert pair lists via atomics
// ---------------------------------------------------------------------------
__global__ __launch_bounds__(256) void router_kernel(
    const float* __restrict__ hidden, const float* __restrict__ rw,
    const float* __restrict__ bias, float* __restrict__ out,
    __bf16* __restrict__ hbf,
    int* __restrict__ counts, int* __restrict__ pair_token,
    float* __restrict__ pair_weight)
{
  const int t = blockIdx.x;
  const int tid = threadIdx.x;
  __shared__ float sh[HID];
  __shared__ float part[8][NTOT];
  __shared__ float s_zt;

  const float* hrow = hidden + (size_t)t * HID;
  for (int i = tid; i < HID / 4; i += 256)
    ((float4*)sh)[i] = ((const float4*)hrow)[i];
  __syncthreads();

  // bf16 copy of this hidden row (one v8bf per thread: 256*8 = 2048)
  {
    const int base = tid * 8;
    v8bf v;
#pragma unroll
    for (int j = 0; j < 8; ++j) v[j] = (__bf16)sh[base + j];
    *(v8bf*)(hbf + (size_t)t * HID + base) = v;
  }

  // partial logits: 8 groups x 32 experts
  {
    const int g = tid >> 5, e = tid & 31;
    const float* w = rw + (size_t)e * HID + g * 256;
    const float* hh = sh + g * 256;
    float acc = 0.f;
#pragma unroll 8
    for (int h = 0; h < 256; ++h) acc = fmaf(hh[h], w[h], acc);
    part[g][e] = acc;
  }
  __syncthreads();

  if (tid < 64) {
    const int lane = tid;
    float logit = -INFINITY;
    if (lane < NTOT) {
      float s = 0.f;
#pragma unroll
      for (int g = 0; g < 8; ++g) s += part[g][lane];
      logit = s;
    }
    float m = logit;
#pragma unroll
    for (int off = 32; off; off >>= 1) m = fmaxf(m, __shfl_xor(m, off));
    const float ex = (lane < NTOT) ? expf(logit - m) : 0.f;
    float sum = ex;
#pragma unroll
    for (int off = 32; off; off >>= 1) sum += __shfl_xor(sum, off);
    float sc = (lane < NTOT) ? (ex / sum + bias[lane]) : -INFINITY;

    float zt = 0.f;
#pragma unroll
    for (int it = 0; it < KSEL; ++it) {
      float v = sc; int vid = lane;
#pragma unroll
      for (int off = 32; off; off >>= 1) {
        const float ov = __shfl_xor(v, off);
        const int oid = __shfl_xor(vid, off);
        if (ov > v || (ov == v && oid < vid)) { v = ov; vid = oid; }
      }
      const float wv = v * RSCALE;
      if (vid >= NEXP) {
        zt += wv;                       // identical on all lanes
      } else if (lane == 0) {
        const int pos = atomicAdd(&counts[vid], 1);
        pair_token[vid * TOKENS + pos] = t;
        pair_weight[vid * TOKENS + pos] = wv;
      }
      if (lane == vid) sc = -INFINITY;  // remove winner
    }
    if (lane == 0) s_zt = zt;
  }
  __syncthreads();

  const float zt = s_zt;
  float* orow = out + (size_t)t * HID;
  for (int i = tid; i < HID / 4; i += 256) {
    float4 v = ((const float4*)sh)[i];
    v.x *= zt; v.y *= zt; v.z *= zt; v.w *= zt;
    ((float4*)orow)[i] = v;
  }
}

// ---------------------------------------------------------------------------
__global__ void scan_kernel(const int* __restrict__ counts,
                            int* __restrict__ offsets) {
  if (threadIdx.x == 0) {
    int acc = 0;
#pragma unroll
    for (int e = 0; e < NEXP; ++e) { offsets[e] = acc; acc += counts[e]; }
    offsets[NEXP] = acc;
  }
}

// ---------------------------------------------------------------------------
// GEMM1 (grouped): for expert e, tile of 128 gathered token rows x 64 f-cols.
// Computes gate and up halves, swiglu, folds routing weight, stores act bf16.
// A: bf16 hidden rows (pre-converted). B: fp32 w13, converted during staging
// with transpose into [n][k] LDS layout so b-frags are contiguous b128 reads.
// ---------------------------------------------------------------------------
#define BKPAD 40  // lds row stride in bf16 elements (80B, 16B-aligned)

__global__ __launch_bounds__(256) void gemm1_kernel(
    const __bf16* __restrict__ hbf, const float* __restrict__ w13,
    const int* __restrict__ counts, const int* __restrict__ offsets,
    const int* __restrict__ pair_token, const float* __restrict__ pair_weight,
    __bf16* __restrict__ act)
{
  const int e = blockIdx.z, mt = blockIdx.y, nt = blockIdx.x;
  const int cnt = counts[e];
  const int m0 = mt * 128;
  if (m0 >= cnt) return;
  const int obase = offsets[e];

  __shared__ __bf16 sA[128][BKPAD];
  __shared__ __bf16 sBg[64][BKPAD];
  __shared__ __bf16 sBu[64][BKPAD];
  __shared__ int sTok[128];
  __shared__ float sW[128];

  const int tid = threadIdx.x;
  if (tid < 128) {
    const int m = m0 + tid;
    sTok[tid] = (m < cnt) ? pair_token[e * TOKENS + m] : -1;
    sW[tid] = (m < cnt) ? pair_weight[e * TOKENS + m] : 0.f;
  }
  __syncthreads();

  const float* w13e = w13 + (size_t)e * HID * (2 * FFN);
  const int fbase = nt * 64;

  const int wid = tid >> 6, lane = tid & 63;
  const int wr = wid >> 1, wf = wid & 1;
  const int lrow = lane & 15, lq = lane >> 4;

  v4f accg[4][2], accu[4][2];
#pragma unroll
  for (int mi = 0; mi < 4; ++mi)
#pragma unroll
    for (int fi = 0; fi < 2; ++fi) {
      v4f z = {0.f, 0.f, 0.f, 0.f};
      accg[mi][fi] = z; accu[mi][fi] = z;
    }

  // staging maps
  const int ar = tid >> 1;        // 0..127 (A row)
  const int ac = (tid & 1) * 16;  // 0 or 16 (A col chunk of 16 bf16)
  const int sa_tok = sTok[ar];
  const int bk = tid >> 3;        // 0..31 (B k row)
  const int bn = (tid & 7) * 8;   // 0..56 (B n chunk of 8)

  for (int kt = 0; kt < HID; kt += 32) {
    // ---- stage A (128x32 bf16, direct copy from hbf) ----
    {
      v8bf a0, a1;
      if (sa_tok >= 0) {
        const __bf16* src = hbf + (size_t)sa_tok * HID + kt + ac;
        a0 = *(const v8bf*)src;
        a1 = *(const v8bf*)(src + 8);
      } else {
        a0 = zero_v8bf(); a1 = zero_v8bf();
      }
      *(v8bf*)&sA[ar][ac] = a0;
      *(v8bf*)&sA[ar][ac + 8] = a1;
    }
    // ---- stage B gate & up (32x64 each, fp32 -> bf16, transposed) ----
    {
      const float* srcg = w13e + (size_t)(kt + bk) * (2 * FFN) + fbase + bn;
      const float4 g0 = ((const float4*)srcg)[0];
      const float4 g1 = ((const float4*)srcg)[1];
      const float* srcu = srcg + FFN;
      const float4 u0 = ((const float4*)srcu)[0];
      const float4 u1 = ((const float4*)srcu)[1];
      const float gg[8] = {g0.x, g0.y, g0.z, g0.w, g1.x, g1.y, g1.z, g1.w};
      const float uu[8] = {u0.x, u0.y, u0.z, u0.w, u1.x, u1.y, u1.z, u1.w};
#pragma unroll
      for (int j = 0; j < 8; ++j) {
        sBg[bn + j][bk] = (__bf16)gg[j];
        sBu[bn + j][bk] = (__bf16)uu[j];
      }
    }
    __syncthreads();

    v8bf af[4], bg[2], bu[2];
#pragma unroll
    for (int mi = 0; mi < 4; ++mi)
      af[mi] = *(const v8bf*)&sA[wr * 64 + mi * 16 + lrow][lq * 8];
#pragma unroll
    for (int fi = 0; fi < 2; ++fi) {
      bg[fi] = *(const v8bf*)&sBg[wf * 32 + fi * 16 + lrow][lq * 8];
      bu[fi] = *(const v8bf*)&sBu[wf * 32 + fi * 16 + lrow][lq * 8];
    }
#pragma unroll
    for (int mi = 0; mi < 4; ++mi)
#pragma unroll
      for (int fi = 0; fi < 2; ++fi) {
        accg[mi][fi] = __builtin_amdgcn_mfma_f32_16x16x32_bf16(
            af[mi], bg[fi], accg[mi][fi], 0, 0, 0);
        accu[mi][fi] = __builtin_amdgcn_mfma_f32_16x16x32_bf16(
            af[mi], bu[fi], accu[mi][fi], 0, 0, 0);
      }
    __syncthreads();
  }

  // ---- epilogue: swiglu, fold routing weight, store act (bf16) ----
#pragma unroll
  for (int mi = 0; mi < 4; ++mi) {
#pragma unroll
    for (int fi = 0; fi < 2; ++fi) {
#pragma unroll
      for (int r = 0; r < 4; ++r) {
        const int lr = wr * 64 + mi * 16 + lq * 4 + r;
        const int m = m0 + lr;
        if (m < cnt) {
          const float g = accg[mi][fi][r];
          const float u = accu[mi][fi][r];
          const float sg = g / (1.f + __expf(-g));
          const float val = sg * u * sW[lr];
          const int f = fbase + wf * 32 + fi * 16 + lrow;
          act[(size_t)(obase + m) * FFN + f] = (__bf16)val;
        }
      }
    }
  }
}

// ---------------------------------------------------------------------------
// GEMM2 (grouped): act[cnt x 1024] @ w2[e] (1024 x 2048), atomicAdd into out.
// Routing weight already folded into act rows.
// ---------------------------------------------------------------------------
__global__ __launch_bounds__(256) void gemm2_kernel(
    const __bf16* __restrict__ act, const float* __restrict__ w2,
    const int* __restrict__ counts, const int* __restrict__ offsets,
    const int* __restrict__ pair_token, float* __restrict__ out)
{
  const int e = blockIdx.z, mt = blockIdx.y, nt = blockIdx.x;
  const int cnt = counts[e];
  const int m0 = mt * 128;
  if (m0 >= cnt) return;
  const int obase = offsets[e];

  __shared__ __bf16 sA[128][BKPAD];
  __shared__ __bf16 sB[128][BKPAD];
  __shared__ int sTok[128];

  const int tid = threadIdx.x;
  if (tid < 128) {
    const int m = m0 + tid;
    sTok[tid] = (m < cnt) ? pair_token[e * TOKENS + m] : -1;
  }
  __syncthreads();

  const float* w2e = w2 + (size_t)e * FFN * HID;
  const int n0 = nt * 128;

  const int wid = tid >> 6, lane = tid & 63;
  const int wr = wid >> 1, wc = wid & 1;
  const int lrow = lane & 15, lq = lane >> 4;

  v4f acc[4][4];
#pragma unroll
  for (int mi = 0; mi < 4; ++mi)
#pragma unroll
    for (int ni = 0; ni < 4; ++ni) {
      v4f z = {0.f, 0.f, 0.f, 0.f};
      acc[mi][ni] = z;
    }

  const int ar = tid >> 1;
  const int ac = (tid & 1) * 16;
  const bool avalid = (m0 + ar) < cnt;
  const int bk = tid >> 3;        // 0..31
  const int bn = (tid & 7) * 16;  // 0..112

  for (int kt = 0; kt < FFN; kt += 32) {
    // ---- stage A (128x32 bf16 from act, contiguous rows) ----
    {
      v8bf a0, a1;
      if (avalid) {
        const __bf16* src = act + (size_t)(obase + m0 + ar) * FFN + kt + ac;
        a0 = *(const v8bf*)src;
        a1 = *(const v8bf*)(src + 8);
      } else {
        a0 = zero_v8bf(); a1 = zero_v8bf();
      }
      *(v8bf*)&sA[ar][ac] = a0;
      *(v8bf*)&sA[ar][ac + 8] = a1;
    }
    // ---- stage B (32x128 fp32 -> bf16, transposed) ----
    {
      const float* src = w2e + (size_t)(kt + bk) * HID + n0 + bn;
      const float4 b0 = ((const float4*)src)[0];
      const float4 b1 = ((const float4*)src)[1];
      const float4 b2 = ((const float4*)src)[2];
      const float4 b3 = ((const float4*)src)[3];
      const float bb[16] = {b0.x, b0.y, b0.z, b0.w, b1.x, b1.y, b1.z, b1.w,
                            b2.x, b2.y, b2.z, b2.w, b3.x, b3.y, b3.z, b3.w};
#pragma unroll
      for (int j = 0; j < 16; ++j) sB[bn + j][bk] = (__bf16)bb[j];
    }
    __syncthreads();

    v8bf af[4], bb_[4];
#pragma unroll
    for (int mi = 0; mi < 4; ++mi)
      af[mi] = *(const v8bf*)&sA[wr * 64 + mi * 16 + lrow][lq * 8];
#pragma unroll
    for (int ni = 0; ni < 4; ++ni)
      bb_[ni] = *(const v8bf*)&sB[wc * 64 + ni * 16 + lrow][lq * 8];
#pragma unroll
    for (int mi = 0; mi < 4; ++mi)
#pragma unroll
      for (int ni = 0; ni < 4; ++ni)
        acc[mi][ni] = __builtin_amdgcn_mfma_f32_16x16x32_bf16(
            af[mi], bb_[ni], acc[mi][ni], 0, 0, 0);
    __syncthreads();
  }

  // ---- epilogue: atomicAdd weighted expert output into out ----
#pragma unroll
  for (int mi = 0; mi < 4; ++mi) {
#pragma unroll
    for (int ni = 0; ni < 4; ++ni) {
#pragma unroll
      for (int r = 0; r < 4; ++r) {
        const int lr = wr * 64 + mi * 16 + lq * 4 + r;
        const int m = m0 + lr;
        if (m < cnt) {
          const int t = sTok[lr];
          const int n = n0 + wc * 64 + ni * 16 + lrow;
          atomicAdd(&out[(size_t)t * HID + n], acc[mi][ni][r]);
        }
      }
    }
  }
}

// ---------------------------------------------------------------------------
extern "C" void kernel_launch(void* const* d_in, const int* in_sizes, int n_in,
                              void* d_out, int out_size, void* d_ws, size_t ws_size,
                              hipStream_t stream) {
  const float* hidden = (const float*)d_in[0];
  const float* rw     = (const float*)d_in[1];
  const float* bias   = (const float*)d_in[2];
  const float* w13    = (const float*)d_in[3];
  const float* w2     = (const float*)d_in[4];
  float* out = (float*)d_out;

  // workspace layout (all 256B-aligned):
  //   counts[16], offsets[17], pair_token[16*2048], pair_weight[16*2048],
  //   hbf[2048*2048] bf16, act[8192*1024] bf16   -> ~25.5 MB total
  char* ws = (char*)d_ws;
  int* counts = (int*)ws;
  int* offsets = (int*)(ws + 64);
  int* pair_token = (int*)(ws + 256);
  float* pair_weight = (float*)(ws + 256 + (size_t)NEXP * TOKENS * 4);
  __bf16* hbf = (__bf16*)(ws + 256 + 2 * (size_t)NEXP * TOKENS * 4);
  __bf16* act = hbf + (size_t)TOKENS * HID;

  hipMemsetAsync(counts, 0, 16 * sizeof(int), stream);
  router_kernel<<<TOKENS, 256, 0, stream>>>(hidden, rw, bias, out, hbf,
                                            counts, pair_token, pair_weight);
  scan_kernel<<<1, 64, 0, stream>>>(counts, offsets);
  gemm1_kernel<<<dim3(FFN / 64, TOKENS / 128, NEXP), 256, 0, stream>>>(
      hbf, w13, counts, offsets, pair_token, pair_weight, act);
  gemm2_kernel<<<dim3(HID / 128, TOKENS / 128, NEXP), 256, 0, stream>>>(
      act, w2, counts, offsets, pair_token, out);
}

// Round 2
// 284.260 us; speedup vs baseline: 1.2822x; 1.2822x over previous
//
#include <hip/hip_runtime.h>
#include <hip/hip_bf16.h>
#include <math.h>

#define TOKENS 2048
#define HID 2048
#define FFN 1024
#define NEXP 16
#define NTOT 32
#define KSEL 4
#define RSCALE 2.5f

typedef __bf16 v8bf __attribute__((ext_vector_type(8)));
typedef float v4f __attribute__((ext_vector_type(4)));
typedef unsigned short u16x8v __attribute__((ext_vector_type(8)));

static __device__ __forceinline__ v8bf zero_v8bf() {
  u16x8v z = {0, 0, 0, 0, 0, 0, 0, 0};
  return __builtin_bit_cast(v8bf, z);
}

// Swizzled LDS addressing: row-major [rows][64] bf16 (128B rows, 8 chunks of
// 16B). Physical chunk = chunk ^ (row&7). Spreads any "same column, many
// rows" access across all 32 banks (fix for round-1's 16-way conflicts).
static __device__ __forceinline__ int swz(int row, int chunk) {
  return (row << 6) + ((((unsigned)(chunk ^ row)) & 7u) << 3);
}

// ---------------------------------------------------------------------------
// Router: one block per token. Exact fp32 logits -> softmax -> bias-corrected
// top-4 (lowest-index tie-break), zero-expert folding, writes
// out = zero_total*x, bf16 hidden copy, per-expert (token,weight) lists.
// ---------------------------------------------------------------------------
__global__ __launch_bounds__(256) void router_kernel(
    const float* __restrict__ hidden, const float* __restrict__ rw,
    const float* __restrict__ bias, float* __restrict__ out,
    __bf16* __restrict__ hbf,
    int* __restrict__ counts, int* __restrict__ pair_token,
    float* __restrict__ pair_weight)
{
  const int t = blockIdx.x;
  const int tid = threadIdx.x;
  __shared__ float sh[HID];
  __shared__ float part[8][NTOT];
  __shared__ float s_zt;

  const float* hrow = hidden + (size_t)t * HID;
  for (int i = tid; i < HID / 4; i += 256)
    ((float4*)sh)[i] = ((const float4*)hrow)[i];
  __syncthreads();

  {
    const int base = tid * 8;
    v8bf v;
#pragma unroll
    for (int j = 0; j < 8; ++j) v[j] = (__bf16)sh[base + j];
    *(v8bf*)(hbf + (size_t)t * HID + base) = v;
  }

  {
    const int g = tid >> 5, e = tid & 31;
    const float* w = rw + (size_t)e * HID + g * 256;
    const float* hh = sh + g * 256;
    float acc = 0.f;
#pragma unroll 8
    for (int h = 0; h < 256; ++h) acc = fmaf(hh[h], w[h], acc);
    part[g][e] = acc;
  }
  __syncthreads();

  if (tid < 64) {
    const int lane = tid;
    float logit = -INFINITY;
    if (lane < NTOT) {
      float s = 0.f;
#pragma unroll
      for (int g = 0; g < 8; ++g) s += part[g][lane];
      logit = s;
    }
    float m = logit;
#pragma unroll
    for (int off = 32; off; off >>= 1) m = fmaxf(m, __shfl_xor(m, off));
    const float ex = (lane < NTOT) ? expf(logit - m) : 0.f;
    float sum = ex;
#pragma unroll
    for (int off = 32; off; off >>= 1) sum += __shfl_xor(sum, off);
    float sc = (lane < NTOT) ? (ex / sum + bias[lane]) : -INFINITY;

    float zt = 0.f;
#pragma unroll
    for (int it = 0; it < KSEL; ++it) {
      float v = sc; int vid = lane;
#pragma unroll
      for (int off = 32; off; off >>= 1) {
        const float ov = __shfl_xor(v, off);
        const int oid = __shfl_xor(vid, off);
        if (ov > v || (ov == v && oid < vid)) { v = ov; vid = oid; }
      }
      const float wv = v * RSCALE;
      if (vid >= NEXP) {
        zt += wv;
      } else if (lane == 0) {
        const int pos = atomicAdd(&counts[vid], 1);
        pair_token[vid * TOKENS + pos] = t;
        pair_weight[vid * TOKENS + pos] = wv;
      }
      if (lane == vid) sc = -INFINITY;
    }
    if (lane == 0) s_zt = zt;
  }
  __syncthreads();

  const float zt = s_zt;
  float* orow = out + (size_t)t * HID;
  for (int i = tid; i < HID / 4; i += 256) {
    float4 v = ((const float4*)sh)[i];
    v.x *= zt; v.y *= zt; v.z *= zt; v.w *= zt;
    ((float4*)orow)[i] = v;
  }
}

// ---------------------------------------------------------------------------
__global__ void scan_kernel(const int* __restrict__ counts,
                            int* __restrict__ offsets) {
  if (threadIdx.x == 0) {
    int acc = 0;
#pragma unroll
    for (int e = 0; e < NEXP; ++e) { offsets[e] = acc; acc += counts[e]; }
    offsets[NEXP] = acc;
  }
}

// ---------------------------------------------------------------------------
// GEMM1 (grouped): 128 gathered rows x 64 f-cols (gate+up), BK=64.
// A: bf16 rows staged via swizzled b128 writes.
// B: fp32 w13, each lane loads 8 k-strided dwords (coalesced 256B/instr),
//    converts, writes one k-contiguous v8bf into transposed swizzled LDS.
// All LDS traffic is conflict-free b128.
// ---------------------------------------------------------------------------
__global__ __launch_bounds__(256) void gemm1_kernel(
    const __bf16* __restrict__ hbf, const float* __restrict__ w13,
    const int* __restrict__ counts, const int* __restrict__ offsets,
    const int* __restrict__ pair_token, const float* __restrict__ pair_weight,
    __bf16* __restrict__ act)
{
  const int e = blockIdx.z, mt = blockIdx.y, nt = blockIdx.x;
  const int cnt = counts[e];
  const int m0 = mt * 128;
  if (m0 >= cnt) return;
  const int obase = offsets[e];

  __shared__ __bf16 sA[128 * 64];
  __shared__ __bf16 sBg[64 * 64];
  __shared__ __bf16 sBu[64 * 64];
  __shared__ int sTok[128];
  __shared__ float sW[128];

  const int tid = threadIdx.x;
  if (tid < 128) {
    const int m = m0 + tid;
    sTok[tid] = (m < cnt) ? pair_token[e * TOKENS + m] : -1;
    sW[tid] = (m < cnt) ? pair_weight[e * TOKENS + m] : 0.f;
  }
  __syncthreads();

  const float* w13e = w13 + (size_t)e * HID * (2 * FFN);
  const int fbase = nt * 64;

  const int wid = tid >> 6, lane = tid & 63;
  const int wr = wid >> 1, wf = wid & 1;
  const int lrow = lane & 15, lq = lane >> 4;

  // A staging: 2 threads/row, 4 chunks (32 bf16 = 64B) each
  const int ar = tid >> 1, ac4 = (tid & 1) * 4;
  const int a_tok = sTok[ar];
  const __bf16* a_src =
      (a_tok >= 0) ? (hbf + (size_t)a_tok * HID + ac4 * 8) : nullptr;

  v4f accg[4][2], accu[4][2];
#pragma unroll
  for (int mi = 0; mi < 4; ++mi)
#pragma unroll
    for (int fi = 0; fi < 2; ++fi) {
      v4f z = {0.f, 0.f, 0.f, 0.f};
      accg[mi][fi] = z; accu[mi][fi] = z;
    }

  for (int kt = 0; kt < HID; kt += 64) {
    // ---- stage A ----
    if (a_tok >= 0) {
      const v8bf* s = (const v8bf*)(a_src + kt);
#pragma unroll
      for (int c = 0; c < 4; ++c)
        *(v8bf*)&sA[swz(ar, ac4 + c)] = s[c];
    } else {
#pragma unroll
      for (int c = 0; c < 4; ++c)
        *(v8bf*)&sA[swz(ar, ac4 + c)] = zero_v8bf();
    }
    // ---- stage B (gate & up), transposed via k-strided dword loads ----
#pragma unroll
    for (int h = 0; h < 2; ++h) {
      __bf16* dst = h ? sBu : sBg;
#pragma unroll
      for (int ku = 0; ku < 2; ++ku) {
        const int kb = ku * 32 + wid * 8;
        const float* src =
            w13e + (size_t)(kt + kb) * (2 * FFN) + h * FFN + fbase + lane;
        v8bf v;
#pragma unroll
        for (int j = 0; j < 8; ++j) v[j] = (__bf16)src[(size_t)j * (2 * FFN)];
        *(v8bf*)&dst[swz(lane, ku * 4 + wid)] = v;
      }
    }
    __syncthreads();

#pragma unroll
    for (int ks = 0; ks < 2; ++ks) {
      v8bf a[4], bg[2], bu[2];
#pragma unroll
      for (int mi = 0; mi < 4; ++mi)
        a[mi] = *(const v8bf*)&sA[swz(wr * 64 + mi * 16 + lrow, ks * 4 + lq)];
#pragma unroll
      for (int fi = 0; fi < 2; ++fi) {
        bg[fi] = *(const v8bf*)&sBg[swz(wf * 32 + fi * 16 + lrow, ks * 4 + lq)];
        bu[fi] = *(const v8bf*)&sBu[swz(wf * 32 + fi * 16 + lrow, ks * 4 + lq)];
      }
#pragma unroll
      for (int mi = 0; mi < 4; ++mi)
#pragma unroll
        for (int fi = 0; fi < 2; ++fi) {
          accg[mi][fi] = __builtin_amdgcn_mfma_f32_16x16x32_bf16(
              a[mi], bg[fi], accg[mi][fi], 0, 0, 0);
          accu[mi][fi] = __builtin_amdgcn_mfma_f32_16x16x32_bf16(
              a[mi], bu[fi], accu[mi][fi], 0, 0, 0);
        }
    }
    __syncthreads();
  }

  // ---- epilogue: swiglu, fold routing weight, store act (bf16) ----
#pragma unroll
  for (int mi = 0; mi < 4; ++mi) {
#pragma unroll
    for (int fi = 0; fi < 2; ++fi) {
#pragma unroll
      for (int r = 0; r < 4; ++r) {
        const int lr = wr * 64 + mi * 16 + lq * 4 + r;
        const int m = m0 + lr;
        if (m < cnt) {
          const float g = accg[mi][fi][r];
          const float u = accu[mi][fi][r];
          const float sg = g / (1.f + __expf(-g));
          const float val = sg * u * sW[lr];
          const int f = fbase + wf * 32 + fi * 16 + lrow;
          act[(size_t)(obase + m) * FFN + f] = (__bf16)val;
        }
      }
    }
  }
}

// ---------------------------------------------------------------------------
// GEMM2 (grouped): act[cnt x 1024] @ w2[e] (1024 x 2048), BK=64, tile 128x128,
// atomicAdd into out. Same swizzled-LDS / strided-dword-B staging structure.
// ---------------------------------------------------------------------------
__global__ __launch_bounds__(256) void gemm2_kernel(
    const __bf16* __restrict__ act, const float* __restrict__ w2,
    const int* __restrict__ counts, const int* __restrict__ offsets,
    const int* __restrict__ pair_token, float* __restrict__ out)
{
  const int e = blockIdx.z, mt = blockIdx.y, nt = blockIdx.x;
  const int cnt = counts[e];
  const int m0 = mt * 128;
  if (m0 >= cnt) return;
  const int obase = offsets[e];

  __shared__ __bf16 sA[128 * 64];
  __shared__ __bf16 sB[128 * 64];
  __shared__ int sTok[128];

  const int tid = threadIdx.x;
  if (tid < 128) {
    const int m = m0 + tid;
    sTok[tid] = (m < cnt) ? pair_token[e * TOKENS + m] : -1;
  }
  __syncthreads();

  const float* w2e = w2 + (size_t)e * FFN * HID;
  const int n0 = nt * 128;

  const int wid = tid >> 6, lane = tid & 63;
  const int wr = wid >> 1, wc = wid & 1;
  const int lrow = lane & 15, lq = lane >> 4;

  const int ar = tid >> 1, ac4 = (tid & 1) * 4;
  const bool avalid = (m0 + ar) < cnt;
  const __bf16* a_src = act + (size_t)(obase + m0 + ar) * FFN + ac4 * 8;

  v4f acc[4][4];
#pragma unroll
  for (int mi = 0; mi < 4; ++mi)
#pragma unroll
    for (int ni = 0; ni < 4; ++ni) {
      v4f z = {0.f, 0.f, 0.f, 0.f};
      acc[mi][ni] = z;
    }

  for (int kt = 0; kt < FFN; kt += 64) {
    // ---- stage A ----
    if (avalid) {
      const v8bf* s = (const v8bf*)(a_src + kt);
#pragma unroll
      for (int c = 0; c < 4; ++c)
        *(v8bf*)&sA[swz(ar, ac4 + c)] = s[c];
    } else {
#pragma unroll
      for (int c = 0; c < 4; ++c)
        *(v8bf*)&sA[swz(ar, ac4 + c)] = zero_v8bf();
    }
    // ---- stage B transposed: n rows 0..127, k cols 0..63 ----
#pragma unroll
    for (int nh = 0; nh < 2; ++nh) {
#pragma unroll
      for (int ku = 0; ku < 2; ++ku) {
        const int kb = ku * 32 + wid * 8;
        const float* src = w2e + (size_t)(kt + kb) * HID + n0 + nh * 64 + lane;
        v8bf v;
#pragma unroll
        for (int j = 0; j < 8; ++j) v[j] = (__bf16)src[(size_t)j * HID];
        *(v8bf*)&sB[swz(nh * 64 + lane, ku * 4 + wid)] = v;
      }
    }
    __syncthreads();

#pragma unroll
    for (int ks = 0; ks < 2; ++ks) {
      v8bf a[4], b[4];
#pragma unroll
      for (int mi = 0; mi < 4; ++mi)
        a[mi] = *(const v8bf*)&sA[swz(wr * 64 + mi * 16 + lrow, ks * 4 + lq)];
#pragma unroll
      for (int ni = 0; ni < 4; ++ni)
        b[ni] = *(const v8bf*)&sB[swz(wc * 64 + ni * 16 + lrow, ks * 4 + lq)];
#pragma unroll
      for (int mi = 0; mi < 4; ++mi)
#pragma unroll
        for (int ni = 0; ni < 4; ++ni)
          acc[mi][ni] = __builtin_amdgcn_mfma_f32_16x16x32_bf16(
              a[mi], b[ni], acc[mi][ni], 0, 0, 0);
    }
    __syncthreads();
  }

  // ---- epilogue: atomicAdd weighted expert output into out ----
#pragma unroll
  for (int mi = 0; mi < 4; ++mi) {
#pragma unroll
    for (int ni = 0; ni < 4; ++ni) {
#pragma unroll
      for (int r = 0; r < 4; ++r) {
        const int lr = wr * 64 + mi * 16 + lq * 4 + r;
        const int m = m0 + lr;
        if (m < cnt) {
          const int t = sTok[lr];
          const int n = n0 + wc * 64 + ni * 16 + lrow;
          atomicAdd(&out[(size_t)t * HID + n], acc[mi][ni][r]);
        }
      }
    }
  }
}

// ---------------------------------------------------------------------------
extern "C" void kernel_launch(void* const* d_in, const int* in_sizes, int n_in,
                              void* d_out, int out_size, void* d_ws, size_t ws_size,
                              hipStream_t stream) {
  const float* hidden = (const float*)d_in[0];
  const float* rw     = (const float*)d_in[1];
  const float* bias   = (const float*)d_in[2];
  const float* w13    = (const float*)d_in[3];
  const float* w2     = (const float*)d_in[4];
  float* out = (float*)d_out;

  char* ws = (char*)d_ws;
  int* counts = (int*)ws;
  int* offsets = (int*)(ws + 64);
  int* pair_token = (int*)(ws + 256);
  float* pair_weight = (float*)(ws + 256 + (size_t)NEXP * TOKENS * 4);
  __bf16* hbf = (__bf16*)(ws + 256 + 2 * (size_t)NEXP * TOKENS * 4);
  __bf16* act = hbf + (size_t)TOKENS * HID;

  hipMemsetAsync(counts, 0, 16 * sizeof(int), stream);
  router_kernel<<<TOKENS, 256, 0, stream>>>(hidden, rw, bias, out, hbf,
                                            counts, pair_token, pair_weight);
  scan_kernel<<<1, 64, 0, stream>>>(counts, offsets);
  gemm1_kernel<<<dim3(FFN / 64, TOKENS / 128, NEXP), 256, 0, stream>>>(
      hbf, w13, counts, offsets, pair_token, pair_weight, act);
  gemm2_kernel<<<dim3(HID / 128, TOKENS / 128, NEXP), 256, 0, stream>>>(
      act, w2, counts, offsets, pair_token, out);
}